// Round 1
// 696.191 us; speedup vs baseline: 1.1765x; 1.1765x over previous
//
#include <hip/hip_runtime.h>
#include <hip/hip_bf16.h>

#define NODES 100000
#define EDGES 1600000
#define DIM   128

typedef __bf16 bf16x8 __attribute__((ext_vector_type(8)));
typedef float  f32x4  __attribute__((ext_vector_type(4)));
typedef float  f32x2  __attribute__((ext_vector_type(2)));

// ================= edge-index dtype detection =================
// Reference declares int64; harness doc says int32. If int64 (<2^31 values),
// every odd dword of the buffer is 0. 64 random indices all-zero-odd: p~0.
__global__ void detect_kernel(const unsigned int* __restrict__ ei, int* __restrict__ flags) {
    const unsigned long long nz = __ballot(ei[2 * threadIdx.x + 1] != 0);
    if (threadIdx.x == 0) flags[0] = (nz == 0ULL) ? 1 : 0;
}

__device__ __forceinline__ int load_idx(const void* ei, long long pos, int m64) {
    return m64 ? (int)((const long long*)ei)[pos] : ((const int*)ei)[pos];
}

// ================= degree / normalization =================
__global__ __launch_bounds__(256) void zero_int_kernel(int* __restrict__ p, int n) {
    int i = blockIdx.x * 256 + threadIdx.x;
    if (i < n) p[i] = 0;
}

__global__ __launch_bounds__(256) void count_deg_kernel(const void* __restrict__ ei,
                                                        const int* __restrict__ flags,
                                                        int* __restrict__ deg, int e_cnt) {
    const int m64 = flags[0];
    int i = blockIdx.x * 256 + threadIdx.x;
    if (i < e_cnt) atomicAdd(&deg[load_idx(ei, (long long)EDGES + i, m64)], 1);
}

__global__ __launch_bounds__(256) void make_dis_kernel(const int* __restrict__ deg,
                                                       float* __restrict__ dis, int n) {
    int i = blockIdx.x * 256 + threadIdx.x;
    if (i < n) dis[i] = rsqrtf((float)deg[i] + 1.0f);
}

// ================= CSR build =================
__global__ __launch_bounds__(256) void scan1_kernel(const int* __restrict__ deg,
                                                    int* __restrict__ offs,
                                                    int* __restrict__ bsum, int n) {
    __shared__ int sm[256];
    const int t = threadIdx.x, i = blockIdx.x * 256 + t;
    const int v = (i < n) ? deg[i] : 0;
    sm[t] = v;
    __syncthreads();
    for (int d = 1; d < 256; d <<= 1) {     // Hillis-Steele inclusive scan
        const int add = (t >= d) ? sm[t - d] : 0;
        __syncthreads();
        sm[t] += add;
        __syncthreads();
    }
    if (i < n) offs[i] = sm[t] - v;         // block-local exclusive
    if (t == 255) bsum[blockIdx.x] = sm[255];
}

// parallel single-block scan over the block sums (nb = 391 <= 512)
__global__ __launch_bounds__(512) void scan2_kernel(const int* __restrict__ bsum,
                                                    int* __restrict__ boff,
                                                    int* __restrict__ offs, int nb, int n) {
    __shared__ int sm[512];
    const int t = threadIdx.x;
    const int v = (t < nb) ? bsum[t] : 0;
    sm[t] = v;
    __syncthreads();
    for (int d = 1; d < 512; d <<= 1) {
        const int add = (t >= d) ? sm[t - d] : 0;
        __syncthreads();
        sm[t] += add;
        __syncthreads();
    }
    if (t < nb) boff[t] = sm[t] - v;        // exclusive
    if (t == nb - 1) offs[n] = sm[t];       // == E
}

__global__ __launch_bounds__(256) void scan3_kernel(int* __restrict__ offs,
                                                    const int* __restrict__ boff,
                                                    int* __restrict__ cursor, int n) {
    const int i = blockIdx.x * 256 + threadIdx.x;
    if (i < n) {
        const int o = offs[i] + boff[blockIdx.x];
        offs[i]   = o;
        cursor[i] = o;
    }
}

// packed CSR record: {src, coef-as-bits} — one 8B load per edge in aggregate
__global__ __launch_bounds__(256) void fill_csr_kernel(const void* __restrict__ ei,
                                                       const int* __restrict__ flags,
                                                       const float* __restrict__ dis,
                                                       int* __restrict__ cursor,
                                                       int2* __restrict__ csr,
                                                       int e_cnt) {
    const int m64 = flags[0];
    int e = blockIdx.x * 256 + threadIdx.x;
    if (e >= e_cnt) return;
    const int s = load_idx(ei, e, m64);
    const int d = load_idx(ei, (long long)EDGES + e, m64);
    const int idx = atomicAdd(&cursor[d], 1);   // int atomic: safe on any memory
    int2 rec;
    rec.x = s;
    rec.y = __float_as_int(dis[s] * dis[d]);
    csr[idx] = rec;
}

// ================= GEMM: fp32 [M x 128] @ fp32 [128 x 128] -> fp32 =================
// bf16 MFMA inside. Fragment index math identical to the verified kernel:
//   B: b[j] = W[(kt*32 + quad*8 + j)*128 + ct*16 + l15]
//   A: a[j] = A[row0 + l15][kt*32 + quad*8 + j]
//   C/D: row = row0 + quad*4 + r, col = ct*16 + l15
// New structure: 16 rows per wave (64/block), B streamed from cache each ct,
// small register file -> ~6 waves/SIMD at 1563 blocks (was 1.5 waves/SIMD).
template <int RELU_BIAS>
__global__ __launch_bounds__(256) void gemm128_kernel(
    const float* __restrict__ A, const float* __restrict__ W,
    const float* __restrict__ bias, float* __restrict__ out, int M)
{
    const int wave = threadIdx.x >> 6;
    const int lane = threadIdx.x & 63;
    const int l15  = lane & 15;
    const int quad = lane >> 4;

    const int row0 = blockIdx.x * 64 + wave * 16;
    if (row0 >= M) return;  // wave-uniform

    const int arow  = row0 + l15;
    const int arowc = arow < M ? arow : (M - 1);
    const float* ap = A + (size_t)arowc * DIM + quad * 8;
    bf16x8 afrag[4];
#pragma unroll
    for (int kt = 0; kt < 4; kt++) {
        const f32x4 lo = *(const f32x4*)(ap + kt * 32);
        const f32x4 hi = *(const f32x4*)(ap + kt * 32 + 4);
        bf16x8 r;
#pragma unroll
        for (int j = 0; j < 4; j++) { r[j] = (__bf16)lo[j]; r[j + 4] = (__bf16)hi[j]; }
        afrag[kt] = r;
    }

#pragma unroll
    for (int ct = 0; ct < 8; ct++) {
        f32x4 c = {0.f, 0.f, 0.f, 0.f};
#pragma unroll
        for (int kt = 0; kt < 4; kt++) {
            bf16x8 b;
#pragma unroll
            for (int j = 0; j < 8; j++)
                b[j] = (__bf16)W[(kt * 32 + quad * 8 + j) * DIM + ct * 16 + l15];
            c = __builtin_amdgcn_mfma_f32_16x16x32_bf16(afrag[kt], b, c, 0, 0, 0);
        }
#pragma unroll
        for (int r = 0; r < 4; r++) {
            const int row = row0 + quad * 4 + r;
            if (row < M) {
                float v = c[r];
                if (RELU_BIAS) {
                    v += bias[ct * 16 + l15];
                    v = v > 0.f ? v : 0.f;
                }
                out[(size_t)row * DIM + ct * 16 + l15] = v;
            }
        }
    }
}

// Dual-weight head GEMM: reads A once, writes relu(A@W1+b1) and relu(A@W2+b2).
__global__ __launch_bounds__(256) void gemm128_dual_kernel(
    const float* __restrict__ A,
    const float* __restrict__ W1, const float* __restrict__ b1,
    const float* __restrict__ W2, const float* __restrict__ b2,
    float* __restrict__ out1, float* __restrict__ out2, int M)
{
    const int wave = threadIdx.x >> 6;
    const int lane = threadIdx.x & 63;
    const int l15  = lane & 15;
    const int quad = lane >> 4;

    const int row0 = blockIdx.x * 64 + wave * 16;
    if (row0 >= M) return;

    const int arow  = row0 + l15;
    const int arowc = arow < M ? arow : (M - 1);
    const float* ap = A + (size_t)arowc * DIM + quad * 8;
    bf16x8 afrag[4];
#pragma unroll
    for (int kt = 0; kt < 4; kt++) {
        const f32x4 lo = *(const f32x4*)(ap + kt * 32);
        const f32x4 hi = *(const f32x4*)(ap + kt * 32 + 4);
        bf16x8 r;
#pragma unroll
        for (int j = 0; j < 4; j++) { r[j] = (__bf16)lo[j]; r[j + 4] = (__bf16)hi[j]; }
        afrag[kt] = r;
    }

#pragma unroll
    for (int ct = 0; ct < 8; ct++) {
        f32x4 c1 = {0.f, 0.f, 0.f, 0.f};
        f32x4 c2 = {0.f, 0.f, 0.f, 0.f};
#pragma unroll
        for (int kt = 0; kt < 4; kt++) {
            bf16x8 bA, bB;
#pragma unroll
            for (int j = 0; j < 8; j++) {
                const int widx = (kt * 32 + quad * 8 + j) * DIM + ct * 16 + l15;
                bA[j] = (__bf16)W1[widx];
                bB[j] = (__bf16)W2[widx];
            }
            c1 = __builtin_amdgcn_mfma_f32_16x16x32_bf16(afrag[kt], bA, c1, 0, 0, 0);
            c2 = __builtin_amdgcn_mfma_f32_16x16x32_bf16(afrag[kt], bB, c2, 0, 0, 0);
        }
        const float bb1 = b1[ct * 16 + l15];
        const float bb2 = b2[ct * 16 + l15];
#pragma unroll
        for (int r = 0; r < 4; r++) {
            const int row = row0 + quad * 4 + r;
            if (row < M) {
                float v1 = c1[r] + bb1; v1 = v1 > 0.f ? v1 : 0.f;
                float v2 = c2[r] + bb2; v2 = v2 > 0.f ? v2 : 0.f;
                out1[(size_t)row * DIM + ct * 16 + l15] = v1;
                out2[(size_t)row * DIM + ct * 16 + l15] = v2;
            }
        }
    }
}

// ================= aggregate (CSR gather, fp32) =================
// out[v] = act( dis[v]^2*xw[v] + sum_p coef[p]*xw[csr[p].src] + bias )
// One wave per node. 16 lanes span the 128-col row (8 cols/lane, 2x f32x4
// 16B loads). The 4 quads of the wave each own edges p ≡ beg+quad (mod 4),
// unrolled x2 -> up to 8 independent row-gathers in flight per wave
// (was 1-2 with the serial 2-col/lane loop -> latency-bound at 34% HBM).
// Cross-quad reduction: shfl_xor 16 then 32.
template <int RELU>
__global__ __launch_bounds__(256) void aggregate_kernel(
    const int* __restrict__ offs, const int2* __restrict__ csr,
    const float* __restrict__ dis, const float* __restrict__ xw,
    const float* __restrict__ bias, float* __restrict__ out, int n)
{
    const int v = blockIdx.x * 4 + (threadIdx.x >> 6);  // one wave per node
    if (v >= n) return;
    const int lane = threadIdx.x & 63;
    const int quad = lane >> 4;        // edge slot 0..3
    const int l15  = lane & 15;
    const int c    = l15 * 8;          // 8 feature cols per lane

    const int beg = offs[v];
    const int end = offs[v + 1];

    f32x4 acc0 = {0.f, 0.f, 0.f, 0.f};
    f32x4 acc1 = {0.f, 0.f, 0.f, 0.f};
    if (quad == 0) {                   // self-loop contribution, once
        const float dv = dis[v];
        const float s2 = dv * dv;
        const float* xr = xw + (size_t)v * DIM + c;
        acc0 = s2 * *(const f32x4*)xr;
        acc1 = s2 * *(const f32x4*)(xr + 4);
    }

    int p = beg + quad;
    for (; p + 4 < end; p += 8) {      // two edges per quad per iteration
        const int2 eA = csr[p];
        const int2 eB = csr[p + 4];
        const float* ra = xw + (size_t)eA.x * DIM + c;
        const float* rb = xw + (size_t)eB.x * DIM + c;
        const f32x4 a0 = *(const f32x4*)ra;
        const f32x4 a1 = *(const f32x4*)(ra + 4);
        const f32x4 b0 = *(const f32x4*)rb;
        const f32x4 b1 = *(const f32x4*)(rb + 4);
        const float ca = __int_as_float(eA.y);
        const float cb = __int_as_float(eB.y);
        acc0 += ca * a0; acc1 += ca * a1;
        acc0 += cb * b0; acc1 += cb * b1;
    }
    if (p < end) {                     // per-quad tail: at most one edge
        const int2 e = csr[p];
        const float* r = xw + (size_t)e.x * DIM + c;
        const float ce = __int_as_float(e.y);
        acc0 += ce * *(const f32x4*)r;
        acc1 += ce * *(const f32x4*)(r + 4);
    }

    // reduce the 4 quad partials (all 64 lanes active: grid is exact)
#pragma unroll
    for (int j = 0; j < 4; j++) {
        acc0[j] += __shfl_xor(acc0[j], 16);
        acc0[j] += __shfl_xor(acc0[j], 32);
        acc1[j] += __shfl_xor(acc1[j], 16);
        acc1[j] += __shfl_xor(acc1[j], 32);
    }

    // quad0 stores cols c..c+3, quad1 stores cols c+4..c+7 (32 lanes, 512B)
    if (quad < 2) {
        f32x4 r = (quad == 0) ? acc0 : acc1;
        const int cc = c + quad * 4;
        r[0] += bias[cc];     r[1] += bias[cc + 1];
        r[2] += bias[cc + 2]; r[3] += bias[cc + 3];
        if (RELU) {
#pragma unroll
            for (int j = 0; j < 4; j++) r[j] = r[j] > 0.f ? r[j] : 0.f;
        }
        *(f32x4*)(out + (size_t)v * DIM + cc) = r;
    }
}

// ================= launcher =================
extern "C" void kernel_launch(void* const* d_in, const int* in_sizes, int n_in,
                              void* d_out, int out_size, void* d_ws, size_t ws_size,
                              hipStream_t stream)
{
    const int N = NODES, E = EDGES;
    const size_t ND = (size_t)N * DIM;

    const float* x  = (const float*)d_in[0];
    const void*  ei = d_in[1];   // [2,E]: src then dst (int32 or int64)
    const float* W1 = (const float*)d_in[2];
    const float* b1 = (const float*)d_in[3];
    const float* W2 = (const float*)d_in[4];
    const float* b2 = (const float*)d_in[5];
    const float* Wv = (const float*)d_in[6];
    const float* bv = (const float*)d_in[7];
    const float* Wt = (const float*)d_in[8];
    const float* bt = (const float*)d_in[9];

    // ws layout (~16 MB)
    char* w = (char*)d_ws;
    int*   flags    = (int*)(w);                  // 256 B
    int*   deg      = (int*)(w + (1 << 10));      // N ints
    float* dis      = (float*)(w + (512 << 10));  // N f32
    int*   offs     = (int*)(w + (1 << 20));      // N+1 ints
    int*   cursor   = (int*)(w + 1572864);        // N ints
    int*   bsum     = (int*)(w + 2097152);        // 391 ints
    int*   boff     = (int*)(w + 2101248);        // 391 ints
    int2*  csr      = (int2*)(w + 3145728);       // E x {src, coef} (12.8 MB)

    // fp32 out slots (ND floats each). Rotation, no reader/writer overlap:
    // xw1->slot2; h1->slot1; xw2->slot2; h->slot0; vis->slot1; txt->slot2
    float* out   = (float*)d_out;
    float* slot0 = out;
    float* slot1 = out + ND;
    float* slot2 = out + 2 * ND;

    const int GN  = (N + 255) / 256;   // 391
    const int GE  = (E + 255) / 256;
    const int GM  = (N + 63) / 64;     // 1563 blocks for GEMM (64 rows/block)
    const int GAG = (N + 3) / 4;       // 25000

    detect_kernel<<<1, 64, 0, stream>>>((const unsigned int*)ei, flags);
    zero_int_kernel<<<GN, 256, 0, stream>>>(deg, N);
    count_deg_kernel<<<GE, 256, 0, stream>>>(ei, flags, deg, E);
    make_dis_kernel<<<GN, 256, 0, stream>>>(deg, dis, N);

    scan1_kernel<<<GN, 256, 0, stream>>>(deg, offs, bsum, N);
    scan2_kernel<<<1, 512, 0, stream>>>(bsum, boff, offs, GN, N);
    scan3_kernel<<<GN, 256, 0, stream>>>(offs, boff, cursor, N);
    fill_csr_kernel<<<GE, 256, 0, stream>>>(ei, flags, dis, cursor, csr, E);

    // ---- layer 1 ----
    gemm128_kernel<0><<<GM, 256, 0, stream>>>(x, W1, nullptr, slot2, N);
    aggregate_kernel<1><<<GAG, 256, 0, stream>>>(offs, csr, dis, slot2, b1, slot1, N);

    // ---- layer 2 ----
    gemm128_kernel<0><<<GM, 256, 0, stream>>>(slot1, W2, nullptr, slot2, N);
    aggregate_kernel<0><<<GAG, 256, 0, stream>>>(offs, csr, dis, slot2, b2, slot0, N);

    // ---- heads (fused: read h once) ----
    gemm128_dual_kernel<<<GM, 256, 0, stream>>>(slot0, Wv, bv, Wt, bt, slot1, slot2, N);
}

// Round 2
// 655.107 us; speedup vs baseline: 1.2503x; 1.0627x over previous
//
#include <hip/hip_runtime.h>
#include <hip/hip_bf16.h>

#define NODES 100000
#define EDGES 1600000
#define DIM   128

typedef __bf16 bf16x8 __attribute__((ext_vector_type(8)));
typedef float  f32x4  __attribute__((ext_vector_type(4)));
typedef float  f32x2  __attribute__((ext_vector_type(2)));

// global_load_lds: per-lane GLOBAL src, wave-uniform LDS base + lane*16 dest.
// Data lands in LDS without consuming VGPR destinations -> in-flight bytes
// no longer capped by register file.
__device__ __forceinline__ void gather16(const float* gp, float* lp) {
    __builtin_amdgcn_global_load_lds(
        (const __attribute__((address_space(1))) void*)gp,
        (__attribute__((address_space(3))) void*)lp, 16, 0, 0);
}

// ================= edge-index dtype detection =================
__global__ void detect_kernel(const unsigned int* __restrict__ ei, int* __restrict__ flags) {
    const unsigned long long nz = __ballot(ei[2 * threadIdx.x + 1] != 0);
    if (threadIdx.x == 0) flags[0] = (nz == 0ULL) ? 1 : 0;
}

__device__ __forceinline__ int load_idx(const void* ei, long long pos, int m64) {
    return m64 ? (int)((const long long*)ei)[pos] : ((const int*)ei)[pos];
}

// ================= degree / normalization =================
__global__ __launch_bounds__(256) void zero_int_kernel(int* __restrict__ p, int n) {
    int i = blockIdx.x * 256 + threadIdx.x;
    if (i < n) p[i] = 0;
}

__global__ __launch_bounds__(256) void count_deg_kernel(const void* __restrict__ ei,
                                                        const int* __restrict__ flags,
                                                        int* __restrict__ deg, int e_cnt) {
    const int m64 = flags[0];
    int i = blockIdx.x * 256 + threadIdx.x;
    if (i < e_cnt) atomicAdd(&deg[load_idx(ei, (long long)EDGES + i, m64)], 1);
}

__global__ __launch_bounds__(256) void make_dis_kernel(const int* __restrict__ deg,
                                                       float* __restrict__ dis, int n) {
    int i = blockIdx.x * 256 + threadIdx.x;
    if (i < n) dis[i] = rsqrtf((float)deg[i] + 1.0f);
}

// ================= CSR build =================
__global__ __launch_bounds__(256) void scan1_kernel(const int* __restrict__ deg,
                                                    int* __restrict__ offs,
                                                    int* __restrict__ bsum, int n) {
    __shared__ int sm[256];
    const int t = threadIdx.x, i = blockIdx.x * 256 + t;
    const int v = (i < n) ? deg[i] : 0;
    sm[t] = v;
    __syncthreads();
    for (int d = 1; d < 256; d <<= 1) {
        const int add = (t >= d) ? sm[t - d] : 0;
        __syncthreads();
        sm[t] += add;
        __syncthreads();
    }
    if (i < n) offs[i] = sm[t] - v;
    if (t == 255) bsum[blockIdx.x] = sm[255];
}

__global__ __launch_bounds__(512) void scan2_kernel(const int* __restrict__ bsum,
                                                    int* __restrict__ boff,
                                                    int* __restrict__ offs, int nb, int n) {
    __shared__ int sm[512];
    const int t = threadIdx.x;
    const int v = (t < nb) ? bsum[t] : 0;
    sm[t] = v;
    __syncthreads();
    for (int d = 1; d < 512; d <<= 1) {
        const int add = (t >= d) ? sm[t - d] : 0;
        __syncthreads();
        sm[t] += add;
        __syncthreads();
    }
    if (t < nb) boff[t] = sm[t] - v;
    if (t == nb - 1) offs[n] = sm[t];
}

__global__ __launch_bounds__(256) void scan3_kernel(int* __restrict__ offs,
                                                    const int* __restrict__ boff,
                                                    int* __restrict__ cursor, int n) {
    const int i = blockIdx.x * 256 + threadIdx.x;
    if (i < n) {
        const int o = offs[i] + boff[blockIdx.x];
        offs[i]   = o;
        cursor[i] = o;
    }
}

__global__ __launch_bounds__(256) void fill_csr_kernel(const void* __restrict__ ei,
                                                       const int* __restrict__ flags,
                                                       const float* __restrict__ dis,
                                                       int* __restrict__ cursor,
                                                       int2* __restrict__ csr,
                                                       int e_cnt) {
    const int m64 = flags[0];
    int e = blockIdx.x * 256 + threadIdx.x;
    if (e >= e_cnt) return;
    const int s = load_idx(ei, e, m64);
    const int d = load_idx(ei, (long long)EDGES + e, m64);
    const int idx = atomicAdd(&cursor[d], 1);
    int2 rec;
    rec.x = s;
    rec.y = __float_as_int(dis[s] * dis[d]);
    csr[idx] = rec;
}

// ================= weight pre-pack: fp32 row-major -> bf16 MFMA fragment layout ==
// dest elem d: j=d&7, l15=(d>>3)&15, quad=(d>>7)&3, kt=(d>>9)&3, ct=(d>>11)&7
// value = (bf16) W[(kt*32+quad*8+j)*128 + ct*16 + l15]
// GEMM then loads B as one coalesced bf16x8 (16B) per lane:
//   frag = Wf[(ct*4+kt)*512 + lane*8 .. +7]
__global__ __launch_bounds__(256) void prep_w_kernel(
    const float* __restrict__ Wa, const float* __restrict__ Wb,
    const float* __restrict__ Wc, const float* __restrict__ Wd,
    __bf16* __restrict__ out)
{
    const int m = blockIdx.x >> 6;                 // which matrix
    const int d = (blockIdx.x & 63) * 256 + threadIdx.x;   // 0..16383
    const float* W = (m == 0) ? Wa : (m == 1) ? Wb : (m == 2) ? Wc : Wd;
    const int j  = d & 7;
    const int l  = (d >> 3) & 15;
    const int q  = (d >> 7) & 3;
    const int kt = (d >> 9) & 3;
    const int ct = (d >> 11) & 7;
    out[m * 16384 + d] = (__bf16)W[(kt * 32 + q * 8 + j) * DIM + ct * 16 + l];
}

// ================= GEMM: fp32 [M x 128] @ prepacked bf16 W -> fp32 =================
// A/C-D fragment math identical to the verified kernel:
//   A: a[j] = A[row0 + l15][kt*32 + quad*8 + j]
//   C/D: row = row0 + quad*4 + r, col = ct*16 + l15
template <int RELU_BIAS>
__global__ __launch_bounds__(256) void gemm128_kernel(
    const float* __restrict__ A, const __bf16* __restrict__ Wf,
    const float* __restrict__ bias, float* __restrict__ out, int M)
{
    const int wave = threadIdx.x >> 6;
    const int lane = threadIdx.x & 63;
    const int l15  = lane & 15;
    const int quad = lane >> 4;

    const int row0 = blockIdx.x * 64 + wave * 16;
    if (row0 >= M) return;  // wave-uniform

    const int arow  = row0 + l15;
    const int arowc = arow < M ? arow : (M - 1);
    const float* ap = A + (size_t)arowc * DIM + quad * 8;
    bf16x8 afrag[4];
#pragma unroll
    for (int kt = 0; kt < 4; kt++) {
        const f32x4 lo = *(const f32x4*)(ap + kt * 32);
        const f32x4 hi = *(const f32x4*)(ap + kt * 32 + 4);
        bf16x8 r;
#pragma unroll
        for (int j = 0; j < 4; j++) { r[j] = (__bf16)lo[j]; r[j + 4] = (__bf16)hi[j]; }
        afrag[kt] = r;
    }

#pragma unroll
    for (int ct = 0; ct < 8; ct++) {
        f32x4 c = {0.f, 0.f, 0.f, 0.f};
#pragma unroll
        for (int kt = 0; kt < 4; kt++) {
            const bf16x8 b = *(const bf16x8*)(Wf + (ct * 4 + kt) * 512 + lane * 8);
            c = __builtin_amdgcn_mfma_f32_16x16x32_bf16(afrag[kt], b, c, 0, 0, 0);
        }
#pragma unroll
        for (int r = 0; r < 4; r++) {
            const int row = row0 + quad * 4 + r;
            if (row < M) {
                float v = c[r];
                if (RELU_BIAS) {
                    v += bias[ct * 16 + l15];
                    v = v > 0.f ? v : 0.f;
                }
                out[(size_t)row * DIM + ct * 16 + l15] = v;
            }
        }
    }
}

// Dual-weight head GEMM: reads A once, writes relu(A@W1+b1) and relu(A@W2+b2).
__global__ __launch_bounds__(256) void gemm128_dual_kernel(
    const float* __restrict__ A,
    const __bf16* __restrict__ Wf1, const float* __restrict__ b1,
    const __bf16* __restrict__ Wf2, const float* __restrict__ b2,
    float* __restrict__ out1, float* __restrict__ out2, int M)
{
    const int wave = threadIdx.x >> 6;
    const int lane = threadIdx.x & 63;
    const int l15  = lane & 15;
    const int quad = lane >> 4;

    const int row0 = blockIdx.x * 64 + wave * 16;
    if (row0 >= M) return;

    const int arow  = row0 + l15;
    const int arowc = arow < M ? arow : (M - 1);
    const float* ap = A + (size_t)arowc * DIM + quad * 8;
    bf16x8 afrag[4];
#pragma unroll
    for (int kt = 0; kt < 4; kt++) {
        const f32x4 lo = *(const f32x4*)(ap + kt * 32);
        const f32x4 hi = *(const f32x4*)(ap + kt * 32 + 4);
        bf16x8 r;
#pragma unroll
        for (int j = 0; j < 4; j++) { r[j] = (__bf16)lo[j]; r[j + 4] = (__bf16)hi[j]; }
        afrag[kt] = r;
    }

#pragma unroll
    for (int ct = 0; ct < 8; ct++) {
        f32x4 c1 = {0.f, 0.f, 0.f, 0.f};
        f32x4 c2 = {0.f, 0.f, 0.f, 0.f};
#pragma unroll
        for (int kt = 0; kt < 4; kt++) {
            const bf16x8 bA = *(const bf16x8*)(Wf1 + (ct * 4 + kt) * 512 + lane * 8);
            const bf16x8 bB = *(const bf16x8*)(Wf2 + (ct * 4 + kt) * 512 + lane * 8);
            c1 = __builtin_amdgcn_mfma_f32_16x16x32_bf16(afrag[kt], bA, c1, 0, 0, 0);
            c2 = __builtin_amdgcn_mfma_f32_16x16x32_bf16(afrag[kt], bB, c2, 0, 0, 0);
        }
        const float bb1 = b1[ct * 16 + l15];
        const float bb2 = b2[ct * 16 + l15];
#pragma unroll
        for (int r = 0; r < 4; r++) {
            const int row = row0 + quad * 4 + r;
            if (row < M) {
                float v1 = c1[r] + bb1; v1 = v1 > 0.f ? v1 : 0.f;
                float v2 = c2[r] + bb2; v2 = v2 > 0.f ? v2 : 0.f;
                out1[(size_t)row * DIM + ct * 16 + l15] = v1;
                out2[(size_t)row * DIM + ct * 16 + l15] = v2;
            }
        }
    }
}

// ================= aggregate (CSR gather via global_load_lds) =================
// out[v] = act( dis[v]^2*xw[v] + sum_p coef[p]*xw[csr[p].src] + bias )
// One wave per node, wave-private 4KB LDS buffer (8 rows x 512B), NO barriers.
// Per batch of 8 edges:
//   - lanes 0..7 load the int2 CSR records (src, coef)
//   - 4x global_load_lds dwordx4: 64 lanes x 16B = 2 gathered rows per instr,
//     per-lane global addr = xw[src_row] + (lane&31)*16; LDS dest consumes no
//     VGPRs -> in-flight bytes/CU ~128KB (was 4KB with reg-dest gathers).
//   - explicit vmcnt(0) drain + sched_barrier, then quads consume rows
//     {quad, quad+4} via ds_read_b128, coefs broadcast by shfl.
template <int RELU>
__global__ __launch_bounds__(256) void aggregate_kernel(
    const int* __restrict__ offs, const int2* __restrict__ csr,
    const float* __restrict__ dis, const float* __restrict__ xw,
    const float* __restrict__ bias, float* __restrict__ out, int n)
{
    __shared__ float sbuf[4][8 * DIM];           // 16 KB / block
    const int wid  = threadIdx.x >> 6;
    const int v    = blockIdx.x * 4 + wid;       // grid is exact: v < n always
    const int lane = threadIdx.x & 63;
    const int quad = lane >> 4;
    const int l15  = lane & 15;
    const int c    = l15 * 8;

    const int beg = offs[v];
    const int end = offs[v + 1];
    const int deg = end - beg;

    f32x4 acc0 = {0.f, 0.f, 0.f, 0.f};
    f32x4 acc1 = {0.f, 0.f, 0.f, 0.f};
    if (quad == 0) {                             // self-loop term, once
        const float dv = dis[v];
        const float s2 = dv * dv;
        const float* xr = xw + (size_t)v * DIM + c;
        acc0 = s2 * *(const f32x4*)xr;
        acc1 = s2 * *(const f32x4*)(xr + 4);
    }

    float* mybuf = &sbuf[wid][0];
    const int half = lane >> 5;                  // 0: even row, 1: odd row
    const int coff = (lane & 31) * 4;            // float offset within row

    for (int b = 0; b < deg; b += 8) {
        const int nr = deg - b < 8 ? deg - b : 8;

        int   src = v;
        float cf  = 0.f;
        if (lane < nr) {
            const int2 rec = csr[beg + b + lane];
            src = rec.x;
            cf  = __int_as_float(rec.y);
        }

#pragma unroll
        for (int i = 0; i < 4; i++) {
            const int r  = 2 * i + half;
            const int rs = __shfl(src, r);
            if (r < nr)                          // exec-masked lanes don't load
                gather16(xw + (size_t)rs * DIM + coff, mybuf + i * 256);
        }

        asm volatile("s_waitcnt vmcnt(0)" ::: "memory");
        __builtin_amdgcn_sched_barrier(0);

#pragma unroll
        for (int k = 0; k < 2; k++) {
            const int r = quad + k * 4;
            const float cr = __shfl(cf, r);
            if (r < nr) {
                const f32x4 x0 = *(const f32x4*)(mybuf + r * DIM + c);
                const f32x4 x1 = *(const f32x4*)(mybuf + r * DIM + c + 4);
                acc0 += cr * x0;
                acc1 += cr * x1;
            }
        }
    }

    // reduce the 4 quad partials
#pragma unroll
    for (int j = 0; j < 4; j++) {
        acc0[j] += __shfl_xor(acc0[j], 16);
        acc0[j] += __shfl_xor(acc0[j], 32);
        acc1[j] += __shfl_xor(acc1[j], 16);
        acc1[j] += __shfl_xor(acc1[j], 32);
    }

    if (quad < 2) {
        f32x4 r = (quad == 0) ? acc0 : acc1;
        const int cc = c + quad * 4;
        r[0] += bias[cc];     r[1] += bias[cc + 1];
        r[2] += bias[cc + 2]; r[3] += bias[cc + 3];
        if (RELU) {
#pragma unroll
            for (int j = 0; j < 4; j++) r[j] = r[j] > 0.f ? r[j] : 0.f;
        }
        *(f32x4*)(out + (size_t)v * DIM + cc) = r;
    }
}

// ================= launcher =================
extern "C" void kernel_launch(void* const* d_in, const int* in_sizes, int n_in,
                              void* d_out, int out_size, void* d_ws, size_t ws_size,
                              hipStream_t stream)
{
    const int N = NODES, E = EDGES;
    const size_t ND = (size_t)N * DIM;

    const float* x  = (const float*)d_in[0];
    const void*  ei = d_in[1];
    const float* W1 = (const float*)d_in[2];
    const float* b1 = (const float*)d_in[3];
    const float* W2 = (const float*)d_in[4];
    const float* b2 = (const float*)d_in[5];
    const float* Wv = (const float*)d_in[6];
    const float* bv = (const float*)d_in[7];
    const float* Wt = (const float*)d_in[8];
    const float* bt = (const float*)d_in[9];

    // ws layout (~16.2 MB)
    char* w = (char*)d_ws;
    int*    flags  = (int*)(w);
    int*    deg    = (int*)(w + (1 << 10));
    float*  dis    = (float*)(w + (512 << 10));
    int*    offs   = (int*)(w + (1 << 20));
    int*    cursor = (int*)(w + 1572864);
    int*    bsum   = (int*)(w + 2097152);
    int*    boff   = (int*)(w + 2101248);
    int2*   csr    = (int2*)(w + 3145728);        // E x 8B, ends at 15,945,728
    __bf16* wf     = (__bf16*)(w + 16000000);     // 4 x 16384 bf16 = 128 KB
    __bf16* wf1 = wf, *wf2 = wf + 16384, *wfv = wf + 32768, *wft = wf + 49152;

    float* out   = (float*)d_out;
    float* slot0 = out;
    float* slot1 = out + ND;
    float* slot2 = out + 2 * ND;

    const int GN  = (N + 255) / 256;   // 391
    const int GE  = (E + 255) / 256;
    const int GM  = (N + 63) / 64;     // 1563
    const int GAG = (N + 3) / 4;       // 25000 (exact: N = 4*25000)

    detect_kernel<<<1, 64, 0, stream>>>((const unsigned int*)ei, flags);
    zero_int_kernel<<<GN, 256, 0, stream>>>(deg, N);
    count_deg_kernel<<<GE, 256, 0, stream>>>(ei, flags, deg, E);
    make_dis_kernel<<<GN, 256, 0, stream>>>(deg, dis, N);
    prep_w_kernel<<<256, 256, 0, stream>>>(W1, W2, Wv, Wt, wf);

    scan1_kernel<<<GN, 256, 0, stream>>>(deg, offs, bsum, N);
    scan2_kernel<<<1, 512, 0, stream>>>(bsum, boff, offs, GN, N);
    scan3_kernel<<<GN, 256, 0, stream>>>(offs, boff, cursor, N);
    fill_csr_kernel<<<GE, 256, 0, stream>>>(ei, flags, dis, cursor, csr, E);

    // ---- layer 1 ----
    gemm128_kernel<0><<<GM, 256, 0, stream>>>(x, wf1, nullptr, slot2, N);
    aggregate_kernel<1><<<GAG, 256, 0, stream>>>(offs, csr, dis, slot2, b1, slot1, N);

    // ---- layer 2 ----
    gemm128_kernel<0><<<GM, 256, 0, stream>>>(slot1, wf2, nullptr, slot2, N);
    aggregate_kernel<0><<<GAG, 256, 0, stream>>>(offs, csr, dis, slot2, b2, slot0, N);

    // ---- heads (fused: read h once) ----
    gemm128_dual_kernel<<<GM, 256, 0, stream>>>(slot0, wfv, bv, wft, bt, slot1, slot2, N);
}